// Round 12
// baseline (283.695 us; speedup 1.0000x reference)
//
#include <hip/hip_runtime.h>
#include <hip/hip_cooperative_groups.h>
#include <stdint.h>

namespace cg = cooperative_groups;
typedef unsigned long long u64;

static constexpr int BB  = 16;
static constexpr int HH  = 720;
static constexpr int WW  = 1280;
static constexpr int HWP = HH * WW;                    // 921600
static constexpr int WORDS_X = WW / 64;                // 20
static constexpr long long OUT_ELEMS = (long long)BB * 3 * HWP;  // 44236800
static constexpr size_t OUT_BYTES = (size_t)OUT_ELEMS * 4;
static constexpr size_t PLANE_B = (size_t)BB * HH * WORDS_X * 8; // 1843200
static constexpr int N16 = (int)(OUT_ELEMS / 16);      // 2764800
// fallback coop output config
static constexpr int KGRID = 512;
static constexpr int KNT = KGRID * 256;
static constexpr int OSLOT = (N16 + KNT - 1) / KNT;    // 22

typedef short v4s __attribute__((ext_vector_type(4)));
union QW { u64 u; v4s v; uint2 p; };

// ---------------------------------------------------------------------------
// Branchless exact direction bin == floor((mod(atan2(gy,gx),pi)+pi/8)/(pi/4))%4.
// ---------------------------------------------------------------------------
__device__ __forceinline__ int dirbin_b(int gx, int gy)
{
    int u  = (gy < 0) ? -gx : gx;
    int vv = gy < 0 ? -gy : gy;
    int A  = u < 0 ? -u : u;
    int b2 = 2 * A * A;
    int tt = vv + A;
    int dd = vv - A;
    bool P1 = (tt * tt < b2);
    bool P2 = (dd < 0) || (dd * dd < b2);
    return P1 ? 0 : (P2 ? ((u > 0) ? 1 : 3) : 2);
}

// ---------------------------------------------------------------------------
// Kernel 1 (r10 config — best measured): fused quantize + Sobel +
// channel-argmax + NMS + threshold.  64x16 tiles, float2 staging,
// single-pass Sobel, 32-bit packed extraction.
// ---------------------------------------------------------------------------
__global__ __launch_bounds__(256)
void k_gradnms(const float* __restrict__ x, u64* __restrict__ splane,
               u64* __restrict__ wplane)
{
    __shared__ __align__(16) u64 qimg[20][72];  // ch0|ch1|ch2|0 u16x4; 11.25KB
    __shared__ int mtile[18][68];               // mag | bin<<12

    const int blk = blockIdx.x;
    const int bx = blk % 20;
    const int t1 = blk / 20;
    const int by = t1 % 45;
    const int b  = t1 / 45;
    const int x0 = bx << 6, y0 = by << 4;
    const float* bp = x + (size_t)b * 3 * HWP;

    // staging: 20 rows x 34 column-pairs (cols 0..67 <-> global x0-2..x0+65)
    for (int i = threadIdx.x; i < 20 * 34; i += 256) {
        int r   = i / 34;
        int pc  = i - r * 34;
        int col = pc * 2;
        int gy = y0 - 2 + r;   gy = gy < 0 ? 0 : (gy > HH - 1 ? HH - 1 : gy);
        int gx = x0 - 2 + col;
        const float* row = bp + (size_t)gy * WW;
        float a0, a1, b0, b1, c0, c1;
        if (gx >= 0 && gx + 1 < WW) {          // aligned fast path (gx even)
            float2 fa = *(const float2*)(row + gx);
            float2 fb = *(const float2*)(row + HWP + gx);
            float2 fc = *(const float2*)(row + 2 * HWP + gx);
            a0 = fa.x; a1 = fa.y; b0 = fb.x; b1 = fb.y; c0 = fc.x; c1 = fc.y;
        } else {                                // border clamp (rare)
            int g0 = gx     < 0 ? 0 : (gx     > WW - 1 ? WW - 1 : gx);
            int g1 = gx + 1 < 0 ? 0 : (gx + 1 > WW - 1 ? WW - 1 : gx + 1);
            a0 = row[g0];           a1 = row[g1];
            b0 = row[HWP + g0];     b1 = row[HWP + g1];
            c0 = row[2 * HWP + g0]; c1 = row[2 * HWP + g1];
        }
        // trunc == floor for non-negative values
        uint32_t qa0 = (uint32_t)(fminf(fmaxf(a0, 0.f), 1.f) * 255.f);
        uint32_t qb0 = (uint32_t)(fminf(fmaxf(b0, 0.f), 1.f) * 255.f);
        uint32_t qc0 = (uint32_t)(fminf(fmaxf(c0, 0.f), 1.f) * 255.f);
        uint32_t qa1 = (uint32_t)(fminf(fmaxf(a1, 0.f), 1.f) * 255.f);
        uint32_t qb1 = (uint32_t)(fminf(fmaxf(b1, 0.f), 1.f) * 255.f);
        uint32_t qc1 = (uint32_t)(fminf(fmaxf(c1, 0.f), 1.f) * 255.f);
        ulonglong2 wv;
        wv.x = (u64)(qa0 | (qb0 << 16)) | ((u64)qc0 << 32);
        wv.y = (u64)(qa1 | (qb1 << 16)) | ((u64)qc1 << 32);
        *(ulonglong2*)&qimg[r][col] = wv;       // (r*72+col)*8 is 16B-aligned
    }
    __syncthreads();

    // Sobel: 18 rows x 14 groups x 5 px, separable column sums
    if (threadIdx.x < 18 * 14) {
        int r  = threadIdx.x / 14;
        int g  = threadIdx.x - r * 14;
        int c0 = g * 5;
        int my = y0 - 1 + r;
        bool rowok = (my >= 0 && my < HH);
        v4s s[7], t[7];
#pragma unroll
        for (int k = 0; k < 7; ++k) {
            QW w0, w1, w2;
            w0.u = qimg[r    ][c0 + k];
            w1.u = qimg[r + 1][c0 + k];
            w2.u = qimg[r + 2][c0 + k];
            s[k] = w0.v + w1.v + w1.v + w2.v;
            t[k] = w2.v - w0.v;
        }
        int mx0 = x0 - 1 + c0;
#pragma unroll
        for (int j = 0; j < 5; ++j) {
            int c = c0 + j;
            if (c >= 66) continue;
            int pk = 0;
            int mx = mx0 + j;
            if (rowok && mx >= 0 && mx < WW) {
                v4s gx4 = s[j + 2] - s[j];
                v4s gy4 = t[j] + t[j + 1] + t[j + 1] + t[j + 2];
                v4s ax = __builtin_elementwise_max(gx4, -gx4);
                v4s ay = __builtin_elementwise_max(gy4, -gy4);
                QW mq; mq.v = ax + ay;
                int m0 = (int)(mq.p.x & 0xffffu);
                int m1 = (int)(mq.p.x >> 16);
                int m2 = (int)(mq.p.y & 0xffffu);
                int bm = m0, bi = 0;                   // first-max tie
                if (m1 > bm) { bm = m1; bi = 1; }
                if (m2 > bm) { bm = m2; bi = 2; }
                QW gq; gq.v = gx4;
                QW hq; hq.v = gy4;
                uint32_t gw = (bi == 2) ? gq.p.y : gq.p.x;
                uint32_t hw = (bi == 2) ? hq.p.y : hq.p.x;
                int hi16 = (bi == 1) ? 16 : 0;
                int bgx = (int)(short)(gw >> hi16);
                int bgy = (int)(short)(hw >> hi16);
                pk = bm | (dirbin_b(bgx, bgy) << 12);
            }
            mtile[r][c] = pk;
        }
    }
    __syncthreads();

    const int v = threadIdx.x >> 6, l = threadIdx.x & 63;
#pragma unroll
    for (int k = 0; k < 4; ++k) {
        int ry = v * 4 + k;
        int pk = mtile[ry + 1][l + 1];
        int m = pk & 0xFFF, bin = pk >> 12;
        int dy = (bin == 0) ? 0 : 1;
        int dx = (bin == 2) ? 0 : ((bin == 3) ? -1 : 1);
        int n1 = mtile[ry + 1 + dy][l + 1 + dx] & 0xFFF;
        int n2 = mtile[ry + 1 - dy][l + 1 - dx] & 0xFFF;
        int keep = (m >= n1) && (m >= n2);
        u64 sB = __ballot(keep && m >= 77);
        u64 wB = __ballot(keep && m >= 26);
        if (l == 0) {
            size_t rb = ((size_t)b * HH + (y0 + ry)) * WORDS_X + bx;
            splane[rb] = sB;
            wplane[rb] = wB;
        }
    }
}

// ---------------------------------------------------------------------------
// Bit helpers
// ---------------------------------------------------------------------------
__device__ __forceinline__ u64 sh_up(u64 x, int k) {
    int l = threadIdx.x & 63;
    u64 y = __shfl(x, l - k, 64);
    return (l >= k) ? y : 0ull;
}
__device__ __forceinline__ u64 sh_dn(u64 x, int k) {
    int l = threadIdx.x & 63;
    u64 y = __shfl(x, l + k, 64);
    return (l + k < 64) ? y : 0ull;
}
__device__ __forceinline__ u64 dil(u64 x) { return x | (x << 1) | (x >> 1); }

__device__ __forceinline__ u64 hflood_L(u64 f, u64 w) {
    u64 p = w;
    f |= p & (f << 1);  p &= (p << 1);
    f |= p & (f << 2);  p &= (p << 2);
    f |= p & (f << 4);  p &= (p << 4);
    f |= p & (f << 8);  p &= (p << 8);
    f |= p & (f << 16); p &= (p << 16);
    f |= p & (f << 32);
    return f;
}
__device__ __forceinline__ u64 hflood_R(u64 f, u64 w) {
    u64 p = w;
    f |= p & (f >> 1);  p &= (p >> 1);
    f |= p & (f >> 2);  p &= (p >> 2);
    f |= p & (f >> 4);  p &= (p >> 4);
    f |= p & (f >> 8);  p &= (p >> 8);
    f |= p & (f >> 16); p &= (p >> 16);
    f |= p & (f >> 32);
    return f;
}

// ---------------------------------------------------------------------------
// Kernel 2 (v10): r7 structure (16 blocks x 768, LDS seam exchange +
// frontier gating) with a LATENCY-light in-round converge.
// r7's in-round cost was dominated by the h-closure cross-word CARRY CHAIN:
// 20 words x ~12 dependent ops x 2 directions ~ 1000-cycle serial critical
// path per iteration (VALUBusy 0.02% => latency-bound, not issue-bound).
// In-round converge now uses (a) word-local hflood (20 independent chains,
// ~150-cycle path) and (b) a BFS step whose neighbor term includes the own
// row's dilated word + cross-word corner bits, so horizontal cross-word
// propagation costs one cheap iteration per crossing.  Exit condition =
// BFS added nothing => F is h-closed (word-local pass applied; cross-word
// covered by corner bits) and v/diag-closed: exact same fixed point.
// Initial whole-image closure keeps the exact carry-chain version.
// ---------------------------------------------------------------------------
__global__ __launch_bounds__(768, 3)
void k_hyst_local(u64* __restrict__ splane, const u64* __restrict__ wplane)
{
    __shared__ u64 sTop[12][20], sBot[12][20];
    __shared__ int schg[2];

    const int b = blockIdx.x;
    const int r = threadIdx.x;
    const int l = threadIdx.x & 63;
    const int v = threadIdx.x >> 6;
    const bool valid = r < HH;
    const size_t base = ((size_t)b * HH + (valid ? r : 0)) * WORDS_X;

    u64 W[20], F[20];
#pragma unroll
    for (int j = 0; j < 20; ++j) {
        W[j] = valid ? wplane[base + j] : 0ull;
        F[j] = valid ? splane[base + j] : 0ull;
    }

    // exact converge with cross-word carry chains (used once, initially)
    auto converge_full = [&]() {
        while (true) {
            u64 carry = 0;
#pragma unroll
            for (int j = 0; j < 20; ++j) {
                u64 f = F[j] | (W[j] & carry);
                f = hflood_L(f, W[j]);
                F[j] = f;
                carry = (f >> 63) & 1ull;
            }
            carry = 0;
#pragma unroll
            for (int j = 19; j >= 0; --j) {
                u64 f = F[j] | (W[j] & (carry << 63));
                f = hflood_R(f, W[j]);
                F[j] = f;
                carry = f & 1ull;
            }
            int ch = 0;
            u64 po = 0;
            u64 cur = F[0];
#pragma unroll
            for (int j = 0; j < 20; ++j) {
                u64 nx = (j < 19) ? F[j + 1] : 0ull;
                u64 n = dil(cur) | ((po >> 63) & 1ull) | ((nx & 1ull) << 63);
                po = cur; cur = nx;
                u64 add = W[j] & (sh_up(n, 1) | sh_dn(n, 1)) & ~F[j];
                ch |= (add != 0ull);
                F[j] |= add;
            }
            if (!__any(ch)) break;
        }
    };

    // latency-light converge for in-round re-closure (no serial carry chain)
    auto converge_light = [&]() {
        while (true) {
            // word-local horizontal closure: 20 independent dep chains
#pragma unroll
            for (int j = 0; j < 20; ++j) {
                u64 f = hflood_L(F[j], W[j]);
                F[j] = hflood_R(f, W[j]);
            }
            // BFS: horizontal (own row incl. cross-word corners) + vert + diag
            int ch = 0;
            u64 po = 0;
            u64 cur = F[0];
#pragma unroll
            for (int j = 0; j < 20; ++j) {
                u64 nx = (j < 19) ? F[j + 1] : 0ull;
                u64 n = dil(cur) | ((po >> 63) & 1ull) | ((nx & 1ull) << 63);
                po = cur; cur = nx;
                u64 add = W[j] & (n | sh_up(n, 1) | sh_dn(n, 1)) & ~F[j];
                ch |= (add != 0ull);
                F[j] |= add;
            }
            if (!__any(ch)) break;   // BFS-null => h-closed too (see header)
        }
    };

    if (threadIdx.x == 0) { schg[0] = 0; schg[1] = 0; }
    converge_full();                       // initial local closure, all waves

    int iter = 0;
    while (true) {
        const int c = iter & 1;
        if (threadIdx.x == 0) schg[c ^ 1] = 0;   // reset other-parity flag

        // ---- publish seam rows (dilated, cross-word corners included) ----
        if (l == 0 || l == 63) {
#pragma unroll
            for (int j = 0; j < 20; ++j) {
                u64 d = dil(F[j]);
                if (j > 0)  d |= (F[j-1] >> 63) & 1ull;
                if (j < 19) d |= (F[j+1] & 1ull) << 63;
                if (l == 0) sTop[v][j] = d; else sBot[v][j] = d;
            }
        }
        __syncthreads();

        // ---- gather seam seeds; flood only if they add new bits ----
        int anynb = 0;
#pragma unroll
        for (int j = 0; j < 20; ++j) {
            u64 s = 0ull;
            if (l == 0  && v > 0)  s = sBot[v-1][j];
            else if (l == 63 && v < 11) s = sTop[v+1][j];
            u64 add = W[j] & s & ~F[j];
            anynb |= (add != 0ull);
            F[j] |= add;
        }
        if (__any(anynb)) {                 // wave-uniform (frontier gating)
            converge_light();
            schg[c] = 1;                    // benign multi-writer race
        }
        __syncthreads();
        if (!schg[c]) break;
        ++iter;
    }

#pragma unroll
    for (int j = 0; j < 20; ++j)
        if (valid) splane[base + j] = F[j];
}

// ---------------------------------------------------------------------------
// Kernel 3a (plain, fast path — planes in d_ws): expand bits -> float output
// ---------------------------------------------------------------------------
__global__ __launch_bounds__(256)
void k_out(const u64* __restrict__ splane, float* __restrict__ out)
{
    int i = blockIdx.x * 256 + threadIdx.x;
    int px  = i * 16;
    int bb  = px / (3 * HWP);
    int rem = px - bb * (3 * HWP);
    int yx  = rem % HWP;
    int y   = yx / WW;
    int xx  = yx - y * WW;
    u64 wv = splane[((size_t)bb * HH + y) * WORDS_X + (xx >> 6)];
    uint32_t bits = (uint32_t)((wv >> (xx & 63)) & 0xFFFFull);
    float4* o4 = (float4*)(out + (size_t)i * 16);
#pragma unroll
    for (int q = 0; q < 4; ++q) {
        float4 fv;
        fv.x = (bits >> (q * 4 + 0)) & 1 ? 1.0f : 0.0f;
        fv.y = (bits >> (q * 4 + 1)) & 1 ? 1.0f : 0.0f;
        fv.z = (bits >> (q * 4 + 2)) & 1 ? 1.0f : 0.0f;
        fv.w = (bits >> (q * 4 + 3)) & 1 ? 1.0f : 0.0f;
        o4[q] = fv;
    }
}

// ---------------------------------------------------------------------------
// Kernel 3b (coop fallback — planes in d_out tail): capture, sync, write
// ---------------------------------------------------------------------------
__global__ __launch_bounds__(256, 4)
void k_out_capture(const u64* __restrict__ splane, float* __restrict__ out)
{
    cg::grid_group grid = cg::this_grid();
    const int gtid = blockIdx.x * 256 + threadIdx.x;
    uint32_t vals[OSLOT];
#pragma unroll
    for (int n = 0; n < OSLOT; ++n) {
        int i = gtid + n * KNT;
        if (i < N16) {
            int px  = i * 16;
            int bb  = px / (3 * HWP);
            int rem = px - bb * (3 * HWP);
            int yx  = rem % HWP;
            int y   = yx / WW;
            int xx  = yx - y * WW;
            u64 wv = splane[((size_t)bb * HH + y) * WORDS_X + (xx >> 6)];
            vals[n] = (uint32_t)((wv >> (xx & 63)) & 0xFFFFull);
        }
    }
    grid.sync();
#pragma unroll
    for (int n = 0; n < OSLOT; ++n) {
        int i = gtid + n * KNT;
        if (i < N16) {
            uint32_t bits = vals[n];
            float4* o4 = (float4*)(out + (size_t)i * 16);
#pragma unroll
            for (int q = 0; q < 4; ++q) {
                float4 fv;
                fv.x = (bits >> (q * 4 + 0)) & 1 ? 1.0f : 0.0f;
                fv.y = (bits >> (q * 4 + 1)) & 1 ? 1.0f : 0.0f;
                fv.z = (bits >> (q * 4 + 2)) & 1 ? 1.0f : 0.0f;
                fv.w = (bits >> (q * 4 + 3)) & 1 ? 1.0f : 0.0f;
                o4[q] = fv;
            }
        }
    }
}

// ---------------------------------------------------------------------------
extern "C" void kernel_launch(void* const* d_in, const int* in_sizes, int n_in,
                              void* d_out, int out_size, void* d_ws, size_t ws_size,
                              hipStream_t stream)
{
    const float* x = (const float*)d_in[0];
    float* out = (float*)d_out;

    const bool use_ws = (d_ws != nullptr) && (ws_size >= 2 * PLANE_B);
    u64 *splane, *wplane;
    if (use_ws) {
        splane = (u64*)d_ws;
        wplane = (u64*)((char*)d_ws + PLANE_B);
    } else {
        char* tail = (char*)d_out + OUT_BYTES;
        wplane = (u64*)(tail - PLANE_B);
        splane = (u64*)(tail - 2 * PLANE_B);
    }

    k_gradnms<<<20 * 45 * BB, 256, 0, stream>>>(x, splane, wplane);
    k_hyst_local<<<BB, 768, 0, stream>>>(splane, wplane);

    if (use_ws) {
        k_out<<<N16 / 256, 256, 0, stream>>>(splane, out);
    } else {
        void* args[] = { (void*)&splane, (void*)&out };
        hipLaunchCooperativeKernel((void*)k_out_capture, dim3(KGRID), dim3(256),
                                   args, 0, stream);
    }
}

// Round 13
// 203.185 us; speedup vs baseline: 1.3962x; 1.3962x over previous
//
#include <hip/hip_runtime.h>
#include <hip/hip_cooperative_groups.h>
#include <stdint.h>

namespace cg = cooperative_groups;
typedef unsigned long long u64;

static constexpr int BB  = 16;
static constexpr int HH  = 720;
static constexpr int WW  = 1280;
static constexpr int HWP = HH * WW;                    // 921600
static constexpr int WORDS_X = WW / 64;                // 20
static constexpr long long OUT_ELEMS = (long long)BB * 3 * HWP;  // 44236800
static constexpr size_t OUT_BYTES = (size_t)OUT_ELEMS * 4;
static constexpr size_t PLANE_B = (size_t)BB * HH * WORDS_X * 8; // 1843200
static constexpr int N16 = (int)(OUT_ELEMS / 16);      // 2764800
// fallback coop output config
static constexpr int KGRID = 512;
static constexpr int KNT = KGRID * 256;
static constexpr int OSLOT = (N16 + KNT - 1) / KNT;    // 22
// gradnms grid: 20 x 45 x 16 = 14400 blocks; 14400 % 8 == 0 -> bijective swz
static constexpr int NWG   = 20 * 45 * BB;
static constexpr int CPX   = NWG / 8;                  // 1800 blocks per XCD

typedef short v4s __attribute__((ext_vector_type(4)));
union QW { u64 u; v4s v; uint2 p; };

// ---------------------------------------------------------------------------
// Branchless exact direction bin == floor((mod(atan2(gy,gx),pi)+pi/8)/(pi/4))%4.
// ---------------------------------------------------------------------------
__device__ __forceinline__ int dirbin_b(int gx, int gy)
{
    int u  = (gy < 0) ? -gx : gx;
    int vv = gy < 0 ? -gy : gy;
    int A  = u < 0 ? -u : u;
    int b2 = 2 * A * A;
    int tt = vv + A;
    int dd = vv - A;
    bool P1 = (tt * tt < b2);
    bool P2 = (dd < 0) || (dd * dd < b2);
    return P1 ? 0 : (P2 ? ((u > 0) ? 1 : 3) : 2);
}

// ---------------------------------------------------------------------------
// Kernel 1 (r10 config + XCD swizzle + bank-pad): fused quantize + Sobel +
// channel-argmax + NMS + threshold.  64x16 tiles, float2 staging,
// single-pass Sobel, 32-bit packed extraction.
// - XCD swizzle: adjacent tiles (sharing halos in L2) map to the same XCD.
// - qimg stride 74 (16B-aligned): Sobel's 14 groups/row hit 14 distinct
//   even bank-pairs (10g mod 32 distinct) -> fewer LDS bank conflicts.
// ---------------------------------------------------------------------------
__global__ __launch_bounds__(256)
void k_gradnms(const float* __restrict__ x, u64* __restrict__ splane,
               u64* __restrict__ wplane)
{
    __shared__ __align__(16) u64 qimg[20][74];  // ch0|ch1|ch2|0 u16x4; 11.6KB
    __shared__ int mtile[18][68];               // mag | bin<<12

    // bijective XCD-aware swizzle (NWG % 8 == 0)
    const int bid = blockIdx.x;
    const int blk = (bid & 7) * CPX + (bid >> 3);
    const int bx = blk % 20;
    const int t1 = blk / 20;
    const int by = t1 % 45;
    const int b  = t1 / 45;
    const int x0 = bx << 6, y0 = by << 4;
    const float* bp = x + (size_t)b * 3 * HWP;

    // staging: 20 rows x 34 column-pairs (cols 0..67 <-> global x0-2..x0+65)
    for (int i = threadIdx.x; i < 20 * 34; i += 256) {
        int r   = i / 34;
        int pc  = i - r * 34;
        int col = pc * 2;
        int gy = y0 - 2 + r;   gy = gy < 0 ? 0 : (gy > HH - 1 ? HH - 1 : gy);
        int gx = x0 - 2 + col;
        const float* row = bp + (size_t)gy * WW;
        float a0, a1, b0, b1, c0, c1;
        if (gx >= 0 && gx + 1 < WW) {          // aligned fast path (gx even)
            float2 fa = *(const float2*)(row + gx);
            float2 fb = *(const float2*)(row + HWP + gx);
            float2 fc = *(const float2*)(row + 2 * HWP + gx);
            a0 = fa.x; a1 = fa.y; b0 = fb.x; b1 = fb.y; c0 = fc.x; c1 = fc.y;
        } else {                                // border clamp (rare)
            int g0 = gx     < 0 ? 0 : (gx     > WW - 1 ? WW - 1 : gx);
            int g1 = gx + 1 < 0 ? 0 : (gx + 1 > WW - 1 ? WW - 1 : gx + 1);
            a0 = row[g0];           a1 = row[g1];
            b0 = row[HWP + g0];     b1 = row[HWP + g1];
            c0 = row[2 * HWP + g0]; c1 = row[2 * HWP + g1];
        }
        // trunc == floor for non-negative values
        uint32_t qa0 = (uint32_t)(fminf(fmaxf(a0, 0.f), 1.f) * 255.f);
        uint32_t qb0 = (uint32_t)(fminf(fmaxf(b0, 0.f), 1.f) * 255.f);
        uint32_t qc0 = (uint32_t)(fminf(fmaxf(c0, 0.f), 1.f) * 255.f);
        uint32_t qa1 = (uint32_t)(fminf(fmaxf(a1, 0.f), 1.f) * 255.f);
        uint32_t qb1 = (uint32_t)(fminf(fmaxf(b1, 0.f), 1.f) * 255.f);
        uint32_t qc1 = (uint32_t)(fminf(fmaxf(c1, 0.f), 1.f) * 255.f);
        ulonglong2 wv;
        wv.x = (u64)(qa0 | (qb0 << 16)) | ((u64)qc0 << 32);
        wv.y = (u64)(qa1 | (qb1 << 16)) | ((u64)qc1 << 32);
        *(ulonglong2*)&qimg[r][col] = wv;       // (r*74+col)*8 is 16B-aligned
    }
    __syncthreads();

    // Sobel: 18 rows x 14 groups x 5 px, separable column sums
    if (threadIdx.x < 18 * 14) {
        int r  = threadIdx.x / 14;
        int g  = threadIdx.x - r * 14;
        int c0 = g * 5;
        int my = y0 - 1 + r;
        bool rowok = (my >= 0 && my < HH);
        v4s s[7], t[7];
#pragma unroll
        for (int k = 0; k < 7; ++k) {
            QW w0, w1, w2;
            w0.u = qimg[r    ][c0 + k];
            w1.u = qimg[r + 1][c0 + k];
            w2.u = qimg[r + 2][c0 + k];
            s[k] = w0.v + w1.v + w1.v + w2.v;
            t[k] = w2.v - w0.v;
        }
        int mx0 = x0 - 1 + c0;
#pragma unroll
        for (int j = 0; j < 5; ++j) {
            int c = c0 + j;
            if (c >= 66) continue;
            int pk = 0;
            int mx = mx0 + j;
            if (rowok && mx >= 0 && mx < WW) {
                v4s gx4 = s[j + 2] - s[j];
                v4s gy4 = t[j] + t[j + 1] + t[j + 1] + t[j + 2];
                v4s ax = __builtin_elementwise_max(gx4, -gx4);
                v4s ay = __builtin_elementwise_max(gy4, -gy4);
                QW mq; mq.v = ax + ay;
                int m0 = (int)(mq.p.x & 0xffffu);
                int m1 = (int)(mq.p.x >> 16);
                int m2 = (int)(mq.p.y & 0xffffu);
                int bm = m0, bi = 0;                   // first-max tie
                if (m1 > bm) { bm = m1; bi = 1; }
                if (m2 > bm) { bm = m2; bi = 2; }
                QW gq; gq.v = gx4;
                QW hq; hq.v = gy4;
                uint32_t gw = (bi == 2) ? gq.p.y : gq.p.x;
                uint32_t hw = (bi == 2) ? hq.p.y : hq.p.x;
                int hi16 = (bi == 1) ? 16 : 0;
                int bgx = (int)(short)(gw >> hi16);
                int bgy = (int)(short)(hw >> hi16);
                pk = bm | (dirbin_b(bgx, bgy) << 12);
            }
            mtile[r][c] = pk;
        }
    }
    __syncthreads();

    const int v = threadIdx.x >> 6, l = threadIdx.x & 63;
#pragma unroll
    for (int k = 0; k < 4; ++k) {
        int ry = v * 4 + k;
        int pk = mtile[ry + 1][l + 1];
        int m = pk & 0xFFF, bin = pk >> 12;
        int dy = (bin == 0) ? 0 : 1;
        int dx = (bin == 2) ? 0 : ((bin == 3) ? -1 : 1);
        int n1 = mtile[ry + 1 + dy][l + 1 + dx] & 0xFFF;
        int n2 = mtile[ry + 1 - dy][l + 1 - dx] & 0xFFF;
        int keep = (m >= n1) && (m >= n2);
        u64 sB = __ballot(keep && m >= 77);
        u64 wB = __ballot(keep && m >= 26);
        if (l == 0) {
            size_t rb = ((size_t)b * HH + (y0 + ry)) * WORDS_X + bx;
            splane[rb] = sB;
            wplane[rb] = wB;
        }
    }
}

// ---------------------------------------------------------------------------
// Bit helpers
// ---------------------------------------------------------------------------
__device__ __forceinline__ u64 sh_up(u64 x, int k) {
    int l = threadIdx.x & 63;
    u64 y = __shfl(x, l - k, 64);
    return (l >= k) ? y : 0ull;
}
__device__ __forceinline__ u64 sh_dn(u64 x, int k) {
    int l = threadIdx.x & 63;
    u64 y = __shfl(x, l + k, 64);
    return (l + k < 64) ? y : 0ull;
}
__device__ __forceinline__ u64 dil(u64 x) { return x | (x << 1) | (x >> 1); }

__device__ __forceinline__ u64 hflood_L(u64 f, u64 w) {
    u64 p = w;
    f |= p & (f << 1);  p &= (p << 1);
    f |= p & (f << 2);  p &= (p << 2);
    f |= p & (f << 4);  p &= (p << 4);
    f |= p & (f << 8);  p &= (p << 8);
    f |= p & (f << 16); p &= (p << 16);
    f |= p & (f << 32);
    return f;
}
__device__ __forceinline__ u64 hflood_R(u64 f, u64 w) {
    u64 p = w;
    f |= p & (f >> 1);  p &= (p >> 1);
    f |= p & (f >> 2);  p &= (p >> 2);
    f |= p & (f >> 4);  p &= (p >> 4);
    f |= p & (f >> 8);  p &= (p >> 8);
    f |= p & (f >> 16); p &= (p >> 16);
    f |= p & (f >> 32);
    return f;
}

// ---------------------------------------------------------------------------
// Kernel 2 (r7/r10 exact — proven best of six structures): 16 blocks x 768,
// LDS seam exchange + frontier gating; converge = exact carry-chain
// h-closure + one Jacobi 8-connected BFS step per iteration.  1 row/lane
// (40 u64 state — fits the register file; every fatter-state variant
// spilled and regressed: r6/r9/r11/r12).
// ---------------------------------------------------------------------------
__global__ __launch_bounds__(768, 3)
void k_hyst_local(u64* __restrict__ splane, const u64* __restrict__ wplane)
{
    __shared__ u64 sTop[12][20], sBot[12][20];
    __shared__ int schg[2];

    const int b = blockIdx.x;
    const int r = threadIdx.x;
    const int l = threadIdx.x & 63;
    const int v = threadIdx.x >> 6;
    const bool valid = r < HH;
    const size_t base = ((size_t)b * HH + (valid ? r : 0)) * WORDS_X;

    u64 W[20], F[20];
#pragma unroll
    for (int j = 0; j < 20; ++j) {
        W[j] = valid ? wplane[base + j] : 0ull;
        F[j] = valid ? splane[base + j] : 0ull;
    }

    auto converge_band = [&]() {
        while (true) {
            u64 carry = 0;
#pragma unroll
            for (int j = 0; j < 20; ++j) {
                u64 f = F[j] | (W[j] & carry);
                f = hflood_L(f, W[j]);
                F[j] = f;
                carry = (f >> 63) & 1ull;
            }
            carry = 0;
#pragma unroll
            for (int j = 19; j >= 0; --j) {
                u64 f = F[j] | (W[j] & (carry << 63));
                f = hflood_R(f, W[j]);
                F[j] = f;
                carry = f & 1ull;
            }
            int ch = 0;
            u64 po = 0;
            u64 cur = F[0];
#pragma unroll
            for (int j = 0; j < 20; ++j) {
                u64 nx = (j < 19) ? F[j + 1] : 0ull;
                u64 n = dil(cur) | ((po >> 63) & 1ull) | ((nx & 1ull) << 63);
                po = cur; cur = nx;
                u64 add = W[j] & (sh_up(n, 1) | sh_dn(n, 1)) & ~F[j];
                ch |= (add != 0ull);
                F[j] |= add;
            }
            if (!__any(ch)) break;
        }
    };

    if (threadIdx.x == 0) { schg[0] = 0; schg[1] = 0; }
    converge_band();

    int iter = 0;
    while (true) {
        const int c = iter & 1;
        if (threadIdx.x == 0) schg[c ^ 1] = 0;

        if (l == 0 || l == 63) {
#pragma unroll
            for (int j = 0; j < 20; ++j) {
                u64 d = dil(F[j]);
                if (j > 0)  d |= (F[j-1] >> 63) & 1ull;
                if (j < 19) d |= (F[j+1] & 1ull) << 63;
                if (l == 0) sTop[v][j] = d; else sBot[v][j] = d;
            }
        }
        __syncthreads();

        int anynb = 0;
#pragma unroll
        for (int j = 0; j < 20; ++j) {
            u64 s = 0ull;
            if (l == 0  && v > 0)  s = sBot[v-1][j];
            else if (l == 63 && v < 11) s = sTop[v+1][j];
            u64 add = W[j] & s & ~F[j];
            anynb |= (add != 0ull);
            F[j] |= add;
        }
        if (__any(anynb)) {
            converge_band();
            schg[c] = 1;
        }
        __syncthreads();
        if (!schg[c]) break;
        ++iter;
    }

#pragma unroll
    for (int j = 0; j < 20; ++j)
        if (valid) splane[base + j] = F[j];
}

// ---------------------------------------------------------------------------
// Kernel 3a (plain, fast path — planes in d_ws): expand bits -> float output
// ---------------------------------------------------------------------------
__global__ __launch_bounds__(256)
void k_out(const u64* __restrict__ splane, float* __restrict__ out)
{
    int i = blockIdx.x * 256 + threadIdx.x;
    int px  = i * 16;
    int bb  = px / (3 * HWP);
    int rem = px - bb * (3 * HWP);
    int yx  = rem % HWP;
    int y   = yx / WW;
    int xx  = yx - y * WW;
    u64 wv = splane[((size_t)bb * HH + y) * WORDS_X + (xx >> 6)];
    uint32_t bits = (uint32_t)((wv >> (xx & 63)) & 0xFFFFull);
    float4* o4 = (float4*)(out + (size_t)i * 16);
#pragma unroll
    for (int q = 0; q < 4; ++q) {
        float4 fv;
        fv.x = (bits >> (q * 4 + 0)) & 1 ? 1.0f : 0.0f;
        fv.y = (bits >> (q * 4 + 1)) & 1 ? 1.0f : 0.0f;
        fv.z = (bits >> (q * 4 + 2)) & 1 ? 1.0f : 0.0f;
        fv.w = (bits >> (q * 4 + 3)) & 1 ? 1.0f : 0.0f;
        o4[q] = fv;
    }
}

// ---------------------------------------------------------------------------
// Kernel 3b (coop fallback — planes in d_out tail): capture, sync, write
// ---------------------------------------------------------------------------
__global__ __launch_bounds__(256, 4)
void k_out_capture(const u64* __restrict__ splane, float* __restrict__ out)
{
    cg::grid_group grid = cg::this_grid();
    const int gtid = blockIdx.x * 256 + threadIdx.x;
    uint32_t vals[OSLOT];
#pragma unroll
    for (int n = 0; n < OSLOT; ++n) {
        int i = gtid + n * KNT;
        if (i < N16) {
            int px  = i * 16;
            int bb  = px / (3 * HWP);
            int rem = px - bb * (3 * HWP);
            int yx  = rem % HWP;
            int y   = yx / WW;
            int xx  = yx - y * WW;
            u64 wv = splane[((size_t)bb * HH + y) * WORDS_X + (xx >> 6)];
            vals[n] = (uint32_t)((wv >> (xx & 63)) & 0xFFFFull);
        }
    }
    grid.sync();
#pragma unroll
    for (int n = 0; n < OSLOT; ++n) {
        int i = gtid + n * KNT;
        if (i < N16) {
            uint32_t bits = vals[n];
            float4* o4 = (float4*)(out + (size_t)i * 16);
#pragma unroll
            for (int q = 0; q < 4; ++q) {
                float4 fv;
                fv.x = (bits >> (q * 4 + 0)) & 1 ? 1.0f : 0.0f;
                fv.y = (bits >> (q * 4 + 1)) & 1 ? 1.0f : 0.0f;
                fv.z = (bits >> (q * 4 + 2)) & 1 ? 1.0f : 0.0f;
                fv.w = (bits >> (q * 4 + 3)) & 1 ? 1.0f : 0.0f;
                o4[q] = fv;
            }
        }
    }
}

// ---------------------------------------------------------------------------
extern "C" void kernel_launch(void* const* d_in, const int* in_sizes, int n_in,
                              void* d_out, int out_size, void* d_ws, size_t ws_size,
                              hipStream_t stream)
{
    const float* x = (const float*)d_in[0];
    float* out = (float*)d_out;

    const bool use_ws = (d_ws != nullptr) && (ws_size >= 2 * PLANE_B);
    u64 *splane, *wplane;
    if (use_ws) {
        splane = (u64*)d_ws;
        wplane = (u64*)((char*)d_ws + PLANE_B);
    } else {
        char* tail = (char*)d_out + OUT_BYTES;
        wplane = (u64*)(tail - PLANE_B);
        splane = (u64*)(tail - 2 * PLANE_B);
    }

    k_gradnms<<<NWG, 256, 0, stream>>>(x, splane, wplane);
    k_hyst_local<<<BB, 768, 0, stream>>>(splane, wplane);

    if (use_ws) {
        k_out<<<N16 / 256, 256, 0, stream>>>(splane, out);
    } else {
        void* args[] = { (void*)&splane, (void*)&out };
        hipLaunchCooperativeKernel((void*)k_out_capture, dim3(KGRID), dim3(256),
                                   args, 0, stream);
    }
}